// Round 6
// baseline (9215.867 us; speedup 1.0000x reference)
//
#include <hip/hip_runtime.h>
#include <math.h>

#define TT 200
#define NDIM 1024
#define IDIM 128
#define ODIM 128
#define NB 256

// ws float offsets (total 2,359,296 floats = 9,437,184 B; same budget as R1/R5)
#define JT_OFF 0          // f32 Jt[k][n] = J[n][k]            (1024x1024)
#define BT_OFF 1048576    // f32 Bt[i][n] = B[n][i]            (128x1024)
#define WT_OFF 1179648    // f32 Wt[k][o] = W[o][k]            (1024x128)
#define ST_OFF 1310720    // f32 St[2][1024 n][256 b]  sigmoid(V), TRANSPOSED
#define TH_OFF 1835008    // f32 Th[2][256 b][1024 k]  tanh(V)

// d_out float offsets
#define VT_STRIDE 205824          // 201*1024 per batch
#define ZT_BASE   52690944        // 256*201*1024
#define OUTS_BASE 105381888

__global__ __launch_bounds__(256) void rsnn_prologue(
    const float* __restrict__ J, const float* __restrict__ Bm,
    const float* __restrict__ W, float* __restrict__ ws,
    float* __restrict__ out) {
  int blk = blockIdx.x, tid = threadIdx.x;
  __shared__ float tile[32][33];
  if (blk < 1024) {
    // transpose J (1024x1024) -> Jt[k][n]
    int tk = blk >> 5, tn = blk & 31;
    int k0 = tk * 32, n0 = tn * 32;
    int c = tid & 31, r0 = tid >> 5;
#pragma unroll
    for (int j = 0; j < 4; ++j) {
      int r = r0 + j * 8;
      tile[r][c] = J[(n0 + r) * NDIM + (k0 + c)];
    }
    __syncthreads();
#pragma unroll
    for (int j = 0; j < 4; ++j) {
      int r = r0 + j * 8;
      ws[JT_OFF + (k0 + r) * NDIM + (n0 + c)] = tile[c][r];
    }
  } else if (blk < 1152) {
    // transpose B (1024x128) -> Bt[i][n]
    int b2 = blk - 1024;
    int tn = b2 >> 2, ti = b2 & 3;
    int n0 = tn * 32, i0 = ti * 32;
    int c = tid & 31, r0 = tid >> 5;
#pragma unroll
    for (int j = 0; j < 4; ++j) {
      int r = r0 + j * 8;
      tile[r][c] = Bm[(n0 + r) * IDIM + (i0 + c)];
    }
    __syncthreads();
#pragma unroll
    for (int j = 0; j < 4; ++j) {
      int r = r0 + j * 8;
      ws[BT_OFF + (i0 + r) * NDIM + (n0 + c)] = tile[c][r];
    }
  } else if (blk < 1280) {
    // transpose W (128x1024) -> Wt[k][o]
    int b3 = blk - 1152;
    int to = b3 >> 5, tn = b3 & 31;
    int o0 = to * 32, n0 = tn * 32;
    int c = tid & 31, r0 = tid >> 5;
#pragma unroll
    for (int j = 0; j < 4; ++j) {
      int r = r0 + j * 8;
      tile[r][c] = W[(o0 + r) * NDIM + (n0 + c)];
    }
    __syncthreads();
#pragma unroll
    for (int j = 0; j < 4; ++j) {
      int r = r0 + j * 8;
      ws[WT_OFF + (n0 + r) * ODIM + (o0 + c)] = tile[c][r];
    }
  } else {
    // init parity-0 state + t=0 output planes
    int idx = (blk - 1280) * 256 + tid;   // 0..262143
    ws[ST_OFF + idx] = 0.5f;              // sigmoid(0), any (n,b)
    ws[TH_OFF + idx] = 0.0f;              // tanh(0)
    int b = idx >> 10, n = idx & 1023;
    out[b * VT_STRIDE + n] = 0.0f;
    out[ZT_BASE + b * VT_STRIDE + n] = 0.0f;
  }
}

// 512 blocks (bt=blk>>4: 32x 8-batch tiles, nt=blk&15: 16x 64-neuron tiles),
// 256 threads = 4 waves (kw = w). Bit-exact R1 chains:
//   per (b,n): partials over k-chunks {0-287,288-575,576-863,864-1023+input},
//   reduced ((p0+p1)+p2)+p3. outs: 4x256-k chains, ((0+1)+2)+3.
// S read as wave-uniform contiguous loads from transposed St[n][b] (scalarizable).
__global__ __launch_bounds__(256, 2) void rsnn_step(
    const float* __restrict__ inputs, const float* __restrict__ noise,
    float* __restrict__ ws, float* __restrict__ out, int s) {
  const int tid = threadIdx.x;
  const int l = tid & 63;
  const int w = __builtin_amdgcn_readfirstlane(tid >> 6);  // 0..3
  const int bt = blockIdx.x >> 4, nt = blockIdx.x & 15;
  const int b0 = bt << 3;

  __shared__ float X_lds[IDIM * 12];     // X transposed [i][8b], stride 12
  __shared__ float red[4][8][64];
  __shared__ float red2[4][64];

  if (s < TT) {   // stage X tile (8 batches x 128 inputs), transposed
    const int r = tid >> 5;              // 0..7
    const int c = (tid & 31) << 2;       // 0..124
    float4 xv = *(const float4*)(inputs + ((size_t)(b0 + r) * TT + s) * IDIM + c);
    X_lds[(c + 0) * 12 + r] = xv.x;
    X_lds[(c + 1) * 12 + r] = xv.y;
    X_lds[(c + 2) * 12 + r] = xv.z;
    X_lds[(c + 3) * 12 + r] = xv.w;
  }
  __syncthreads();

  if (s < TT) {
    const float* Stp = ws + ST_OFF + (size_t)(s & 1) * (NDIM * NB);
    const float* JTp = ws + JT_OFF;
    const int n = (nt << 6) + l;
    float acc[8] = {0.f, 0.f, 0.f, 0.f, 0.f, 0.f, 0.f, 0.f};
    const int kb = w * 288;
    const int ke = (kb + 288 < NDIM) ? (kb + 288) : NDIM;
#pragma unroll 4
    for (int k = kb; k < ke; ++k) {
      float jv = JTp[k * NDIM + n];            // coalesced per-lane stream
      const float* sp = Stp + (k << 8) + b0;   // wave-uniform, contiguous 8 floats
      float4 s0 = *(const float4*)sp;
      float4 s1 = *(const float4*)(sp + 4);
      acc[0] = fmaf(s0.x, jv, acc[0]);
      acc[1] = fmaf(s0.y, jv, acc[1]);
      acc[2] = fmaf(s0.z, jv, acc[2]);
      acc[3] = fmaf(s0.w, jv, acc[3]);
      acc[4] = fmaf(s1.x, jv, acc[4]);
      acc[5] = fmaf(s1.y, jv, acc[5]);
      acc[6] = fmaf(s1.z, jv, acc[6]);
      acc[7] = fmaf(s1.w, jv, acc[7]);
    }
    if (w == 3) {  // input projection appended to wave-3's chain (R1 order)
      const float* BTp = ws + BT_OFF;
#pragma unroll 4
      for (int k2 = 0; k2 < IDIM; ++k2) {
        float bv = BTp[k2 * NDIM + n];
        float4 x0 = *(const float4*)&X_lds[k2 * 12];
        float4 x1 = *(const float4*)&X_lds[k2 * 12 + 4];
        acc[0] = fmaf(x0.x, bv, acc[0]);
        acc[1] = fmaf(x0.y, bv, acc[1]);
        acc[2] = fmaf(x0.z, bv, acc[2]);
        acc[3] = fmaf(x0.w, bv, acc[3]);
        acc[4] = fmaf(x1.x, bv, acc[4]);
        acc[5] = fmaf(x1.y, bv, acc[5]);
        acc[6] = fmaf(x1.z, bv, acc[6]);
        acc[7] = fmaf(x1.w, bv, acc[7]);
      }
    }
#pragma unroll
    for (int i = 0; i < 8; ++i) red[w][i][l] = acc[i];
  }

  if (s >= 1) {  // outs for step s-1: 8b x 8o per block, 4 k-chunks across waves
    const float* Tb = ws + TH_OFF + (size_t)(s & 1) * (NB * NDIM);
    const float* WTp = ws + WT_OFF;
    const int i = l >> 3, oo = l & 7;
    const int o = (nt << 3) + oo;
    const float* trow = Tb + (size_t)(b0 + i) * NDIM;
    float acco = 0.f;
    const int k0 = w << 8;
#pragma unroll 4
    for (int k = k0; k < k0 + 256; ++k)
      acco = fmaf(trow[k], WTp[(k << 7) + o], acco);
    red2[w][l] = acco;
  }

  __syncthreads();

  if (s < TT) {
    const int p = (s + 1) & 1;
    float* Stn = ws + ST_OFF + (size_t)p * (NDIM * NB);
    float* Thn = ws + TH_OFF + (size_t)p * (NB * NDIM);
#pragma unroll
    for (int e = 0; e < 2; ++e) {
      const int idx = (e << 8) + tid;      // 0..511 over 8b x 64n
      const int i = idx >> 6, nc = idx & 63;
      float sum = ((red[0][i][nc] + red[1][i][nc]) + red[2][i][nc]) + red[3][i][nc];
      const int b = b0 + i;
      const int n = (nt << 6) + nc;
      float vold = out[b * VT_STRIDE + s * NDIM + n];
      float vnew = 0.9f * vold + 0.1f * sum;
      out[b * VT_STRIDE + (s + 1) * NDIM + n] = vnew;
      float sg = 1.0f / (1.0f + expf(-vnew));
      Stn[(n << 8) + b] = sg;              // transposed scatter (layout only)
      Thn[b * NDIM + n] = tanhf(vnew);
      float zarg = (0.1f * (vnew - 0.4f)) / 0.4f;
      float zs = 1.0f / (1.0f + expf(-zarg));
      float u = noise[(b * TT + s) * NDIM + n];
      out[ZT_BASE + b * VT_STRIDE + (s + 1) * NDIM + n] = (zs > u) ? 1.0f : 0.0f;
    }
  }

  if (s >= 1 && tid < 64) {
    const int i = l >> 3, oo = l & 7;
    float sum = ((red2[0][l] + red2[1][l]) + red2[2][l]) + red2[3][l];
    out[OUTS_BASE + ((size_t)(b0 + i) * TT + (s - 1)) * ODIM + (nt << 3) + oo] = sum;
  }
}

extern "C" void kernel_launch(void* const* d_in, const int* in_sizes, int n_in,
                              void* d_out, int out_size, void* d_ws, size_t ws_size,
                              hipStream_t stream) {
  const float* inputs = (const float*)d_in[0];  // (256,200,128)
  const float* noise  = (const float*)d_in[1];  // (256,200,1024)
  const float* J      = (const float*)d_in[2];  // (1024,1024)
  const float* Bm     = (const float*)d_in[3];  // (1024,128)
  const float* W      = (const float*)d_in[4];  // (128,1024)
  float* out = (float*)d_out;
  float* ws  = (float*)d_ws;

  rsnn_prologue<<<2304, 256, 0, stream>>>(J, Bm, W, ws, out);
  for (int s = 0; s <= TT; ++s) {
    rsnn_step<<<512, 256, 0, stream>>>(inputs, noise, ws, out, s);
  }
}